// Round 5
// baseline (192.760 us; speedup 1.0000x reference)
//
#include <hip/hip_runtime.h>

// ---------------------------------------------------------------------------
// SelfAttentionLayer: out[b,s,c*16+h] = softmax_k( (q.k)/32 masked ) @ v
// R11: 1024-thr blocks, G=4 heads (grid 512 = 1 block/CU x 2 rounds).
//  - Per-thread acc stays 48 regs (12 f32 x 4 heads / 4x more threads) ->
//    X re-staging multiplicity halves (16x, f32-direct == R8's bf16 bytes)
//    and cast_all's X round-trip (~20 us) is gone (only 18 MB cast_w).
//  - 2D wave tiling 4m x 4n: wave = 64 rows x one head's {Q,K,V}; LDS reads
//    drop to 4 af + 3 bf per iter (W amplification 8x -> 4x).
//  - BK=32, Xs AND Ws double-buffered (56 KB), ONE s_barrier per iter:
//    tile t+1 is reg-loaded/DMA'd into the other buffer during compute of t;
//    vmcnt(0)+write+lgkm(0) precede the single barrier. X staging is 8 f32 =
//    8 regs/thread (R10's 32-reg spill cannot recur).
//  - Swizzle: R9's conflict-counter-verified key for 64 B rows: phys 16 B
//    chunk p of row r holds logical p^((r>>1)&3); read chunk quad^((col>>1)&3).
// Attn: per head h, waves wn==h write Q/K/V to LDS; all 16 waves run the
// R5-verified kt-loop on 16-row strips (qt=1). Epilogue: thread t -> row t>>2.
// ---------------------------------------------------------------------------

typedef unsigned short u16;
typedef unsigned int u32;
typedef __attribute__((ext_vector_type(8))) short short8;
typedef __attribute__((ext_vector_type(4))) short short4v;
typedef __attribute__((ext_vector_type(4))) float floatx4;

#if __has_builtin(__builtin_amdgcn_mfma_f32_16x16x16bf16_1k)
#define MFMA16(A, B, C) __builtin_amdgcn_mfma_f32_16x16x16bf16_1k(A, B, C, 0, 0, 0)
#elif __has_builtin(__builtin_amdgcn_mfma_f32_16x16x16_bf16)
#define MFMA16(A, B, C) __builtin_amdgcn_mfma_f32_16x16x16_bf16(A, B, C, 0, 0, 0)
#else
__device__ __forceinline__ floatx4 mfma16_asm(short4v a, short4v b, floatx4 c) {
  floatx4 d;
  asm volatile("v_mfma_f32_16x16x16_bf16 %0, %1, %2, %3"
               : "=v"(d) : "v"(a), "v"(b), "v"(c));
  return d;
}
#define MFMA16(A, B, C) mfma16_asm(A, B, C)
#endif

#if __has_builtin(__builtin_amdgcn_exp2f)
#define EXP2(x) __builtin_amdgcn_exp2f(x)
#else
#define EXP2(x) __expf((x) * 0.6931471805599453f)
#endif

#define QSCALE 0.045084220f  // log2(e)/32, folded into Q

__device__ __forceinline__ u16 f2bf(float f) {
  union { float f; u32 u; } x; x.f = f;
  u32 r = x.u + 0x7fffu + ((x.u >> 16) & 1u);  // RNE
  return (u16)(r >> 16);
}
__device__ __forceinline__ float bf2f(u16 u) {
  union { u32 u; float f; } x; x.u = ((u32)u) << 16;
  return x.f;
}

// packed f32 pair -> bf16 pair (RNE), low half = first operand
__device__ __forceinline__ u32 pkbf(float lo, float hi) {
  u32 d;
  asm("v_cvt_pk_bf16_f32 %0, %1, %2" : "=v"(d) : "v"(lo), "v"(hi));
  return d;
}

// async global->LDS, 16B per lane; LDS dest = wave-uniform base + lane*16
__device__ __forceinline__ void gload16(const void* g, void* l) {
  typedef __attribute__((address_space(1))) const unsigned int gq;
  typedef __attribute__((address_space(3))) unsigned int lq;
  __builtin_amdgcn_global_load_lds((gq*)(size_t)g, (lq*)(size_t)l, 16, 0, 0);
}

#define GK 1024
#define QKS 20   // Qs/Ks row stride (u16): 8B-aligned frags, conflict-free
#define VTS 264  // Vt row stride (u16): 2-way-max banks (free)

// ---------------------------------------------------------------------------
// W-only cast f32 -> bf16: Wq/Wk/Wv, 1024 blocks each (18 MB total, ~3 us)
// ---------------------------------------------------------------------------
__global__ __launch_bounds__(256) void cast_w(const float* __restrict__ wq,
                                              const float* __restrict__ wk,
                                              const float* __restrict__ wv,
                                              u16* __restrict__ WB) {
  int bid = blockIdx.x;
  const float* src = (bid < 1024) ? wq : (bid < 2048) ? wk : wv;
  int seg = bid >> 10;                       // 0,1,2
  int i = ((bid & 1023) * 256 + threadIdx.x) * 4;
  float4 v = *(const float4*)(src + i);
  uint2 o;
  o.x = pkbf(v.x, v.y);
  o.y = pkbf(v.z, v.w);
  *(uint2*)(WB + (size_t)seg * 1024 * 1024 + i) = o;
}

// ---------------------------------------------------------------------------
// Attn kt-loop (R5-verified math): S^T = MFMA(K, Qscaled); p = exp2(st)
// trunc-packed via v_perm; l via MFMA(ones,p); O^T += MFMA(V^T,p).
// qt=1: each of the 16 waves owns a 16-row q-strip.
// ---------------------------------------------------------------------------
template <bool MASKED>
__device__ __forceinline__ void attn_loop1(const u16* __restrict__ Ks,
                                           const u16* __restrict__ Vt,
                                           short4v bq, float mqv,
                                           const float* m_s,
                                           floatx4& oacc, floatx4& lacc,
                                           int col, int quad) {
  const short4v ones = {(short)0x3F80, (short)0x3F80, (short)0x3F80, (short)0x3F80};
#pragma unroll 4
  for (int kt = 0; kt < 16; kt++) {
    const int kb = kt * 16;
    short4v ak = *(const short4v*)(Ks + (kb + col) * QKS + quad * 4);
    short4v av = *(const short4v*)(Vt + col * VTS + kb + quad * 4);
    floatx4 z = {0.f, 0.f, 0.f, 0.f};
    floatx4 st = MFMA16(ak, bq, z);
    float e[4];
#pragma unroll
    for (int i = 0; i < 4; i++) {
      e[i] = EXP2(st[i]);
      if (MASKED) e[i] = (mqv * m_s[kb + quad * 4 + i] > 0.f) ? e[i] : 0.f;
    }
    union { u32 u[2]; short4v s; } pk;
    pk.u[0] = __builtin_amdgcn_perm(__float_as_uint(e[1]), __float_as_uint(e[0]), 0x07060302u);
    pk.u[1] = __builtin_amdgcn_perm(__float_as_uint(e[3]), __float_as_uint(e[2]), 0x07060302u);
    lacc = MFMA16(ones, pk.s, lacc);
    oacc = MFMA16(av, pk.s, oacc);
  }
}

// ---------------------------------------------------------------------------
// Fused kernel. Block = (c0 = (bid>>5)*4 heads, b = bid&31); grid 512 =
// 256 CU x 1 block x 2 rounds. Same-b blocks -> same XCD (bid%8 = b%8):
// 4 f32 X panels (4 MB) per XCD L2, L3 backs the rest.
// Phase 1 (GEMM): [256,192] = X[b][256,1024](f32, cast in-flight) @ W^T.
//   Wave (wm=wave&3, wn=wave>>2): rows [wm*64,+64) x head wn's {Q,K,V}.
//   Per iter: issue W-DMA(t+1)->Wn + 2 f32 loads(t+1) -> 4 af + 3 bf
//   ds_read_b128 + 12 MFMA (tile t) -> vmcnt(0) -> cvt+ds_write(t+1)->Xn
//   -> lgkm(0) -> s_barrier. One barrier/iter; staging hides under compute.
// LDS: Xs 2x[256][32]@0/@16K + Ws 2x[192][32]@32K/@44K = 56 KB; attn (29.3 KB)
// overlays Xs; +1 KB m_s -> ~58 KB -> 1 block/CU (reg-bound anyway).
// ---------------------------------------------------------------------------
__global__ __launch_bounds__(1024, 4) void fused_qkv_attn(const float* __restrict__ x,
                                                          const u16* __restrict__ WB,
                                                          const float* __restrict__ mask,
                                                          float* __restrict__ out) {
  __shared__ __align__(16) u16 smem[28672];  // 57344 B
  // GEMM: Xs0@0 (256*32), Xs1@8192, WsA@16384 (192*32=6144), WsB@22528
  // attn: Qs@0 (256*20), Ks@5120, Vt@10240 (16*264), l_s@14464 (256 f32),
  //       ot overlays @0 (16*257 f32 = 16448 B, inside Qs+Ks = 20480 B)
  __shared__ float m_s[256];

  const int bid = blockIdx.x;
  const int b = bid & 31;
  const int c0 = (bid >> 5) * 4;       // first of 4 heads
  const int t = threadIdx.x;
  const int wave = t >> 6;             // 0..15
  const int lane = t & 63;
  const int col = lane & 15;
  const int quad = lane >> 4;
  const int wm = wave & 3;             // m-group: rows [wm*64, wm*64+64)
  const int wn = wave >> 2;            // n-group = head index 0..3

  u16* const Xs0 = smem;
  u16* const Xs1 = smem + 8192;
  u16* const WsA = smem + 16384;
  u16* const WsB = smem + 22528;

  float mv = (t < 256) ? mask[b * 256 + t] : 1.0f;
  if (t < 256) m_s[t] = mv;
  const int allones = __syncthreads_and(mv > 0.f);

  // ---------------- phase 1: pipelined GEMM, in-flight X cast ----------------
  // X: thread covers row t>>2, 16-B bf16 chunk t&3 (= 8 f32). 2 float4 loads,
  // 4 cvt_pk, 1 swizzled ds_write_b128 per tile.
  const int xr = t >> 2;
  const int xch = t & 3;
  const float* const xg = x + ((size_t)b * 256 + xr) * GK + xch * 8;
  const int xdst = xr * 32 + (xch ^ ((xr >> 1) & 3)) * 8;  // u16 units

  // W: 12 nt-tiles of 16 rows; wave g<12 stages tile g via 1 gload16.
  // Source pre-swizzled (dest linear): lane -> row lane>>2, chunk lane&3.
  const int wr = lane >> 2;
  const int wch = lane & 3;
  const int wsch = wch ^ ((wr >> 1) & 3);
  size_t wsrc = 0;
  if (wave < 12) {
    const int mat = wave % 3, head = wave / 3;
    wsrc = ((size_t)(mat * 1024 + (c0 + head) * 16 + wr)) * GK + wsch * 8;
  }
  const int wdst = wave * 512;         // u16: 16 rows * 32

  floatx4 acc[4][3] = {};  // [mt][Q,K,V] for head wn, rows wm*64+mt*16..

  // read-side un-swizzle (R9 conflict-verified): logical chunk quad at
  // phys quad^((row>>1)&3); row = (tile16)*16 + col -> key = (col>>1)&3.
  const int rpos = (quad ^ ((col >> 1) & 3)) * 8;
  const int abase = (wm * 64 + col) * 32 + rpos;   // + mt*512
  const int bbase = (wn * 48 + col) * 32 + rpos;   // + ntl*512

  // prologue: tile 0 -> Xs0 / WsA
  if (wave < 12) gload16(WB + wsrc, WsA + wdst);
  {
    float4 a0 = *(const float4*)(xg);
    float4 a1 = *(const float4*)(xg + 4);
    asm volatile("s_waitcnt vmcnt(0)" ::: "memory");  // a0/a1 + my W DMA
    uint4 w;
    w.x = pkbf(a0.x, a0.y); w.y = pkbf(a0.z, a0.w);
    w.z = pkbf(a1.x, a1.y); w.w = pkbf(a1.z, a1.w);
    *(uint4*)(Xs0 + xdst) = w;
  }
  asm volatile("s_waitcnt lgkmcnt(0)" ::: "memory");
  __builtin_amdgcn_sched_barrier(0);
  __builtin_amdgcn_s_barrier();
  __builtin_amdgcn_sched_barrier(0);

  auto gemm_step = [&](int knext, const u16* Xc, const u16* Wc, u16* Xn, u16* Wn) {
    float4 a0, a1;
    if (knext >= 0) {                  // issue tile t+1 (other buffers)
      if (wave < 12) gload16(WB + wsrc + knext, Wn + wdst);
      a0 = *(const float4*)(xg + knext);
      a1 = *(const float4*)(xg + knext + 4);
    }
    __builtin_amdgcn_sched_barrier(0); // loads stay above, ds_reads below

    short8 af[4], bf[3];
#pragma unroll
    for (int mt = 0; mt < 4; mt++)
      af[mt] = *(const short8*)(Xc + abase + mt * 512);
#pragma unroll
    for (int n = 0; n < 3; n++)
      bf[n] = *(const short8*)(Wc + bbase + n * 512);
#pragma unroll
    for (int mt = 0; mt < 4; mt++)
#pragma unroll
      for (int n = 0; n < 3; n++)
        acc[mt][n] = __builtin_amdgcn_mfma_f32_16x16x32_bf16(af[mt], bf[n], acc[mt][n], 0, 0, 0);

    if (knext >= 0) {
      asm volatile("s_waitcnt vmcnt(0)" ::: "memory");  // regs + my W DMA landed
      uint4 w;
      w.x = pkbf(a0.x, a0.y); w.y = pkbf(a0.z, a0.w);
      w.z = pkbf(a1.x, a1.y); w.w = pkbf(a1.z, a1.w);
      *(uint4*)(Xn + xdst) = w;
    }
    asm volatile("s_waitcnt lgkmcnt(0)" ::: "memory");  // my reads + writes done
    __builtin_amdgcn_sched_barrier(0);
    __builtin_amdgcn_s_barrier();      // tile t+1 fully staged, t fully read
    __builtin_amdgcn_sched_barrier(0);
  };

  // 32 tiles of BK=32; tile t in buffers (t&1); iter computes t, stages t+1
#pragma unroll 1
  for (int tp = 0; tp < 16; tp++) {
    gemm_step((2 * tp + 1) * 32, Xs0, WsA, Xs1, WsB);                   // t=2tp
    gemm_step((tp == 15) ? -1 : (2 * tp + 2) * 32, Xs1, WsB, Xs0, WsA); // t=2tp+1
  }

  // ---------------- phase 2: attention, 4 heads sequentially ----------------
  u16* const Qs = smem;               // [256][QKS]
  u16* const Ks = smem + 5120;        // [256][QKS]
  u16* const Vt = smem + 10240;       // [16][VTS]
  float* const l_s = (float*)(smem + 14464);
  float* const ot = (float*)smem;     // [16][257] f32, overlays Qs+Ks

#pragma unroll      // full unroll: h compile-time (static acc indices)
  for (int h = 0; h < 4; h++) {
    __syncthreads();  // h=0: GEMM reads done; h>0: prev ot/Vt reads done

    if (wn == h) {    // wave-uniform: head h's owners write Q/K/V
      // C/D layout: row = m-base + quad*4 + r, col(head feature) = lane&15
#pragma unroll
      for (int mt = 0; mt < 4; mt++) {
        const int row = wm * 64 + mt * 16 + quad * 4;
#pragma unroll
        for (int r = 0; r < 4; r++) {
          Qs[(row + r) * QKS + col] = f2bf(acc[mt][0][r] * QSCALE);
          Ks[(row + r) * QKS + col] = f2bf(acc[mt][1][r]);
          Vt[col * VTS + row + r] = f2bf(acc[mt][2][r]);
        }
      }
    }
    __syncthreads();

    const int q0 = wave * 16;
    short4v bq = *(const short4v*)(Qs + (q0 + col) * QKS + quad * 4);
    float mqv = m_s[q0 + col];
    floatx4 oacc = {};
    floatx4 lacc = {};
    if (allones)
      attn_loop1<false>(Ks, Vt, bq, mqv, m_s, oacc, lacc, col, quad);
    else
      attn_loop1<true>(Ks, Vt, bq, mqv, m_s, oacc, lacc, col, quad);

    __syncthreads();  // all waves out of attn before ot overlays Qs/Ks
    if (quad == 0) l_s[q0 + col] = lacc[0];
#pragma unroll
    for (int r = 0; r < 4; r++)
      ot[(quad * 4 + r) * 257 + q0 + col] = oacc[r];
    __syncthreads();

    // epilogue: thread t -> q-row t>>2, features hb..hb+4; 16B coalesced
    const int row = t >> 2;
    const int hb = (t & 3) * 4;
    float l = l_s[row];
    float* op = out + ((size_t)b * 256 + row) * 1024 + (c0 + h) * 16 + hb;
    float o[4];
    if (allones || l > 0.f) {
      float inv = 1.0f / l;
#pragma unroll
      for (int j = 0; j < 4; j++) o[j] = ot[(hb + j) * 257 + row] * inv;
    } else {
      // fully-masked row: reference softmax of uniform -1e9 -> mean of V
#pragma unroll
      for (int j = 0; j < 4; j++) o[j] = 0.f;
      for (int k = 0; k < 256; k++)
#pragma unroll
        for (int j = 0; j < 4; j++) o[j] += bf2f(Vt[(hb + j) * VTS + k]);
#pragma unroll
      for (int j = 0; j < 4; j++) o[j] *= (1.0f / 256.0f);
    }
    float4 rr;
    rr.x = o[0]; rr.y = o[1]; rr.z = o[2]; rr.w = o[3];
    *(float4*)op = rr;
  }
}

// ---------------------------------------------------------------------------
// Launch
// ---------------------------------------------------------------------------
extern "C" void kernel_launch(void* const* d_in, const int* in_sizes, int n_in,
                              void* d_out, int out_size, void* d_ws, size_t ws_size,
                              hipStream_t stream) {
  const float* x    = (const float*)d_in[0];  // [32,256,1024]
  const float* mask = (const float*)d_in[1];  // [32,256]
  const float* Wq   = (const float*)d_in[2];  // [1024,1024]
  const float* Wk   = (const float*)d_in[3];
  const float* Wv   = (const float*)d_in[4];
  float* out = (float*)d_out;

  u16* WB = (u16*)d_ws;                       // [3072][1024] bf16 (Wq,Wk,Wv)

  cast_w<<<3072, 256, 0, stream>>>(Wq, Wk, Wv, WB);
  fused_qkv_attn<<<512, 1024, 0, stream>>>(x, WB, mask, out);
}

// Round 6
// 161.124 us; speedup vs baseline: 1.1963x; 1.1963x over previous
//
#include <hip/hip_runtime.h>

// ---------------------------------------------------------------------------
// SelfAttentionLayer: out[b,s,c*16+h] = softmax_k( (q.k)/32 masked ) @ v
// R12 = R8 (best verified: fused 75.6 us) + two surgical deltas:
//  (1) W-prefetch: Ws double-buffered; W(t+1) DMA issues AFTER sync2 and is
//      drained by the PRE-EXISTING sync1 of iter t+1 (one compute window
//      later). Exposed stage window at sync2 drops 44KB -> 32KB. X path,
//      barrier count, and block structure untouched.
//  (2) T5 s_setprio(1) around the attn MFMA cluster only (m191: +4-7% when
//      co-resident blocks sit at different phases; R8 has 2 blocks/CU).
// R9/R10/R11 post-mortems: in-block pipelining, f32-direct X, and G=4/1024thr
// all lose to R8's 2-block cross-overlap; reverted.
// ---------------------------------------------------------------------------

typedef unsigned short u16;
typedef unsigned int u32;
typedef __attribute__((ext_vector_type(8))) short short8;
typedef __attribute__((ext_vector_type(4))) short short4v;
typedef __attribute__((ext_vector_type(4))) float floatx4;

#if __has_builtin(__builtin_amdgcn_mfma_f32_16x16x16bf16_1k)
#define MFMA16(A, B, C) __builtin_amdgcn_mfma_f32_16x16x16bf16_1k(A, B, C, 0, 0, 0)
#elif __has_builtin(__builtin_amdgcn_mfma_f32_16x16x16_bf16)
#define MFMA16(A, B, C) __builtin_amdgcn_mfma_f32_16x16x16_bf16(A, B, C, 0, 0, 0)
#else
__device__ __forceinline__ floatx4 mfma16_asm(short4v a, short4v b, floatx4 c) {
  floatx4 d;
  asm volatile("v_mfma_f32_16x16x16_bf16 %0, %1, %2, %3"
               : "=v"(d) : "v"(a), "v"(b), "v"(c));
  return d;
}
#define MFMA16(A, B, C) mfma16_asm(A, B, C)
#endif

#if __has_builtin(__builtin_amdgcn_exp2f)
#define EXP2(x) __builtin_amdgcn_exp2f(x)
#else
#define EXP2(x) __expf((x) * 0.6931471805599453f)
#endif

#define QSCALE 0.045084220f  // log2(e)/32, folded into Q

__device__ __forceinline__ u16 f2bf(float f) {
  union { float f; u32 u; } x; x.f = f;
  u32 r = x.u + 0x7fffu + ((x.u >> 16) & 1u);  // RNE
  return (u16)(r >> 16);
}
__device__ __forceinline__ float bf2f(u16 u) {
  union { u32 u; float f; } x; x.u = ((u32)u) << 16;
  return x.f;
}

// async global->LDS, 16B per lane; LDS dest = wave-uniform base + lane*16
__device__ __forceinline__ void gload16(const void* g, void* l) {
  typedef __attribute__((address_space(1))) const unsigned int gq;
  typedef __attribute__((address_space(3))) unsigned int lq;
  __builtin_amdgcn_global_load_lds((gq*)(size_t)g, (lq*)(size_t)l, 16, 0, 0);
}

#define GK 1024
#define QKS 20   // Qs/Ks row stride (u16): 8B-aligned frags, conflict-free
#define VTS 264  // Vt row stride (u16): 2-way-max banks (free)

// ---------------------------------------------------------------------------
// Merged cast f32 -> bf16: X (8192 blocks), Wq/Wk/Wv (1024 blocks each)
// ---------------------------------------------------------------------------
__global__ __launch_bounds__(256) void cast_all(const float* __restrict__ x,
                                                const float* __restrict__ wq,
                                                const float* __restrict__ wk,
                                                const float* __restrict__ wv,
                                                u16* __restrict__ XB,
                                                u16* __restrict__ WB) {
  int bid = blockIdx.x;
  const float* src; u16* dst; int off;
  if (bid < 8192)       { src = x;  dst = XB;                 off = bid; }
  else if (bid < 9216)  { src = wq; dst = WB;                 off = bid - 8192; }
  else if (bid < 10240) { src = wk; dst = WB + 1024 * 1024;   off = bid - 9216; }
  else                  { src = wv; dst = WB + 2 * 1024 * 1024; off = bid - 10240; }
  int i = (off * 256 + threadIdx.x) * 4;
  float4 v = *(const float4*)(src + i);
  u32 lo = (u32)f2bf(v.x) | ((u32)f2bf(v.y) << 16);
  u32 hi = (u32)f2bf(v.z) | ((u32)f2bf(v.w) << 16);
  uint2 o; o.x = lo; o.y = hi;
  *(uint2*)(dst + i) = o;
}

// ---------------------------------------------------------------------------
// Attn kt-loop (R5-verified math, LDS sources): S^T = MFMA(K, Qscaled);
// p = exp2(st) trunc-packed via v_perm; l via MFMA(ones,p); O^T += MFMA(V^T,p)
// qt=2: each of the 8 waves owns a 32-row q-strip.
// T5: setprio(1) around each qt's MFMA cluster (m191 pattern).
// ---------------------------------------------------------------------------
template <bool MASKED>
__device__ __forceinline__ void attn_loop2(const u16* __restrict__ Ks,
                                           const u16* __restrict__ Vt,
                                           const short4v* bq, const float* mqv,
                                           const float* m_s,
                                           floatx4* oacc, floatx4* lacc,
                                           int col, int quad) {
  const short4v ones = {(short)0x3F80, (short)0x3F80, (short)0x3F80, (short)0x3F80};
#pragma unroll 4
  for (int kt = 0; kt < 16; kt++) {
    const int kb = kt * 16;
    short4v ak = *(const short4v*)(Ks + (kb + col) * QKS + quad * 4);
    short4v av = *(const short4v*)(Vt + col * VTS + kb + quad * 4);
    float mk[4];
    if (MASKED) {
#pragma unroll
      for (int i = 0; i < 4; i++) mk[i] = m_s[kb + quad * 4 + i];
    }
#pragma unroll
    for (int qt = 0; qt < 2; qt++) {
      __builtin_amdgcn_s_setprio(1);
      floatx4 z = {0.f, 0.f, 0.f, 0.f};
      floatx4 st = MFMA16(ak, bq[qt], z);
      float e[4];
#pragma unroll
      for (int i = 0; i < 4; i++) {
        e[i] = EXP2(st[i]);
        if (MASKED) e[i] = (mqv[qt] * mk[i] > 0.f) ? e[i] : 0.f;
      }
      union { u32 u[2]; short4v s; } pk;
      pk.u[0] = __builtin_amdgcn_perm(__float_as_uint(e[1]), __float_as_uint(e[0]), 0x07060302u);
      pk.u[1] = __builtin_amdgcn_perm(__float_as_uint(e[3]), __float_as_uint(e[2]), 0x07060302u);
      lacc[qt] = MFMA16(ones, pk.s, lacc[qt]);
      oacc[qt] = MFMA16(av, pk.s, oacc[qt]);
      __builtin_amdgcn_s_setprio(0);
    }
  }
}

// ---------------------------------------------------------------------------
// Fused kernel. Block = (c0 = (bid>>5)*2 heads, b = bid&31); grid 1024.
// Same-b blocks -> same XCD (bid%8 = b%8): XB[b] (512 KB) stays L2-resident.
// Phase 1 (GEMM): [256,96] = X[b][256,1024] @ Wslice[96,1024]^T.
//   8 waves, wave w owns 32-row strip: acc[2 mt][6 nt] (nt = head*3 + {Q,K,V}).
//   BK=64 single-buffer Xs, R8 structure, with Ws double-buffered:
//     sync1 (drains W(t), landed during prev compute) -> X DMA(t) ->
//     sync2 (waits X(t) only, 32KB) -> issue W(t+1) -> compute(Xs, Wc).
//   XOR swizzle (proven): phys chunk p of row holds logical p^(row&7).
// Phase 2 (x2 heads, sequential): Q,K (stride-20) + V^T (stride-264) in LDS ->
//   attn_loop2 -> ot -> epilogue store (thread t -> row t>>1, 8 floats).
// LDS: GEMM Xs[256][64]@0 + WsA[96][64]@32768B + WsB@45056B = 56 KB; attn
// (29.3 KB) overlays Xs; +1 KB m_s -> ~58.4 KB -> 2 blocks/CU (reg-bound).
// ---------------------------------------------------------------------------
__global__ __launch_bounds__(512, 4) void fused_qkv_attn(const u16* __restrict__ XB,
                                                         const u16* __restrict__ WB,
                                                         const float* __restrict__ mask,
                                                         float* __restrict__ out) {
  __shared__ __align__(16) u16 smem[28672];  // 57344 B
  // GEMM: Xs@0 (256*64 = 16384), WsA@16384 (96*64 = 6144), WsB@22528
  // attn: Qs@0 (256*20), Ks@5120, Vt@10240 (16*264, ends 14464),
  //       l_s@14464 (256 f32, ends 14976 < 16384), ot overlays @0 (16*257 f32)
  __shared__ float m_s[256];

  const int bid = blockIdx.x;
  const int b = bid & 31;
  const int c0 = (bid >> 5) * 2;       // first of 2 heads
  const int t = threadIdx.x;
  const int wave = t >> 6;             // 0..7
  const int lane = t & 63;
  const int col = lane & 15;
  const int quad = lane >> 4;

  u16* const Xs = smem;
  u16* const WsA = smem + 16384;
  u16* const WsB = smem + 22528;

  float mv = (t < 256) ? mask[b * 256 + t] : 1.0f;
  if (t < 256) m_s[t] = mv;
  const int allones = __syncthreads_and(mv > 0.f);

  // ---------------- phase 1: GEMM ----------------
  const int r_loc = lane >> 3;          // row within 8-row gload group
  const int sch = (lane & 7) ^ r_loc;   // XOR-swizzled source k-chunk

  // X: wave w stages its own 32 rows (4 gload16 of 8 rows each)
  const size_t xsrc = ((size_t)b * 256 + wave * 32 + r_loc) * GK + sch * 8;
  const int xdst = wave * 2048;         // u16: (wave*32 rows)*64; + g*512

  // W: 12 groups of 8 rows; group g -> nt = g>>1 (nt = head*3 + mat),
  // WB row = (nt%3)*1024 + (c0 + nt/3)*16 + (g&1)*8 + r_loc.
  // wave w stages group w; waves 0-3 also stage group 8+w.
  const int gA = wave;
  const int ntA = gA >> 1;
  const size_t wsrcA =
      ((size_t)((ntA % 3) * 1024 + (c0 + ntA / 3) * 16 + (gA & 1) * 8 + r_loc)) * GK + sch * 8;
  size_t wsrcB = 0;
  const int gB = 8 + wave;
  if (wave < 4) {
    const int ntB = gB >> 1;
    wsrcB = ((size_t)((ntB % 3) * 1024 + (c0 + ntB / 3) * 16 + (gB & 1) * 8 + r_loc)) * GK + sch * 8;
  }

  floatx4 acc[2][6] = {};  // [mt][nt]: m = wave*32+mt*16; nt = head*3+{Q,K,V}

  // prologue: W(0) -> WsA (drained by iter-0 sync1)
  gload16(WB + wsrcA, WsA + gA * 512);
  if (wave < 4) gload16(WB + wsrcB, WsA + gB * 512);

  u16* Wc = WsA;   // W tile for the current iteration
  u16* Wn = WsB;   // prefetch target for the next iteration

  for (int it = 0; it < 16; it++) {
    const int k0 = it * 64;
    __syncthreads();  // sync1: prev ds_reads done; W(it) DMA drained
#pragma unroll
    for (int g = 0; g < 4; g++)
      gload16(XB + xsrc + (size_t)g * 8 * GK + k0, Xs + xdst + g * 512);
    __syncthreads();  // sync2: X(it) landed (W(it) already resident in Wc)

    // W-prefetch for it+1: lands during the compute below + next sync1
    if (it < 15) {
      gload16(WB + wsrcA + k0 + 64, Wn + gA * 512);
      if (wave < 4) gload16(WB + wsrcB + k0 + 64, Wn + gB * 512);
    }

#pragma unroll
    for (int kk = 0; kk < 2; kk++) {
      const int pos = ((kk * 4 + quad) ^ (col & 7)) * 8;
      short8 af[2], bf[6];
#pragma unroll
      for (int mt = 0; mt < 2; mt++)
        af[mt] = *(const short8*)(Xs + (wave * 32 + mt * 16 + col) * 64 + pos);
#pragma unroll
      for (int nt = 0; nt < 6; nt++)
        bf[nt] = *(const short8*)(Wc + (nt * 16 + col) * 64 + pos);
#pragma unroll
      for (int mt = 0; mt < 2; mt++)
#pragma unroll
        for (int nt = 0; nt < 6; nt++)
          acc[mt][nt] = __builtin_amdgcn_mfma_f32_16x16x32_bf16(af[mt], bf[nt], acc[mt][nt], 0, 0, 0);
    }

    u16* tmp = Wc; Wc = Wn; Wn = tmp;  // swap W buffers
  }

  // ---------------- phase 2: attention, 2 heads sequentially ----------------
  u16* const Qs = smem;               // [256][QKS]
  u16* const Ks = smem + 5120;        // [256][QKS]
  u16* const Vt = smem + 10240;       // [16][VTS]
  float* const l_s = (float*)(smem + 14464);
  float* const ot = (float*)smem;     // [16][257] f32, overlays Qs+Ks

#pragma unroll      // full unroll: h must be compile-time (static acc indices)
  for (int h = 0; h < 2; h++) {
    __syncthreads();  // h=0: GEMM reads done; h=1: prev ot/Vt reads done

    // C/D layout: row = m-base + quad*4 + r, col(head feature) = lane&15
#pragma unroll
    for (int mt = 0; mt < 2; mt++) {
      const int row = wave * 32 + mt * 16 + quad * 4;
#pragma unroll
      for (int r = 0; r < 4; r++) {
        Qs[(row + r) * QKS + col] = f2bf(acc[mt][3 * h + 0][r] * QSCALE);
        Ks[(row + r) * QKS + col] = f2bf(acc[mt][3 * h + 1][r]);
        Vt[col * VTS + row + r] = f2bf(acc[mt][3 * h + 2][r]);
      }
    }
    __syncthreads();

    const int q0 = wave * 32;
    short4v bq[2];
    float mqv[2];
#pragma unroll
    for (int qt = 0; qt < 2; qt++) {
      bq[qt] = *(const short4v*)(Qs + (q0 + qt * 16 + col) * QKS + quad * 4);
      mqv[qt] = m_s[q0 + qt * 16 + col];
    }

    floatx4 oacc[2] = {};
    floatx4 lacc[2] = {};
    if (allones)
      attn_loop2<false>(Ks, Vt, bq, mqv, m_s, oacc, lacc, col, quad);
    else
      attn_loop2<true>(Ks, Vt, bq, mqv, m_s, oacc, lacc, col, quad);

    __syncthreads();  // all waves out of attn before ot overlays Qs/Ks
#pragma unroll
    for (int qt = 0; qt < 2; qt++) {
      if (quad == 0) l_s[q0 + qt * 16 + col] = lacc[qt][0];
#pragma unroll
      for (int r = 0; r < 4; r++)
        ot[(quad * 4 + r) * 257 + q0 + qt * 16 + col] = oacc[qt][r];
    }
    __syncthreads();

    // epilogue: thread t -> q-row t>>1, features hb..hb+8; 32B coalesced
    const int row = t >> 1;
    const int hb = (t & 1) * 8;
    float l = l_s[row];
    float* op = out + ((size_t)b * 256 + row) * 1024 + (c0 + h) * 16 + hb;
    float o[8];
    if (allones || l > 0.f) {
      float inv = 1.0f / l;
#pragma unroll
      for (int j = 0; j < 8; j++) o[j] = ot[(hb + j) * 257 + row] * inv;
    } else {
      // fully-masked row: reference softmax of uniform -1e9 -> mean of V
#pragma unroll
      for (int j = 0; j < 8; j++) o[j] = 0.f;
      for (int k = 0; k < 256; k++)
#pragma unroll
        for (int j = 0; j < 8; j++) o[j] += bf2f(Vt[(hb + j) * VTS + k]);
#pragma unroll
      for (int j = 0; j < 8; j++) o[j] *= (1.0f / 256.0f);
    }
#pragma unroll
    for (int g = 0; g < 2; g++) {
      float4 r;
      r.x = o[g * 4 + 0]; r.y = o[g * 4 + 1]; r.z = o[g * 4 + 2]; r.w = o[g * 4 + 3];
      *(float4*)(op + g * 4) = r;
    }
  }
}

// ---------------------------------------------------------------------------
// Launch
// ---------------------------------------------------------------------------
extern "C" void kernel_launch(void* const* d_in, const int* in_sizes, int n_in,
                              void* d_out, int out_size, void* d_ws, size_t ws_size,
                              hipStream_t stream) {
  const float* x    = (const float*)d_in[0];  // [32,256,1024]
  const float* mask = (const float*)d_in[1];  // [32,256]
  const float* Wq   = (const float*)d_in[2];  // [1024,1024]
  const float* Wk   = (const float*)d_in[3];
  const float* Wv   = (const float*)d_in[4];
  float* out = (float*)d_out;

  u16* XB = (u16*)d_ws;                       // [8192][1024] bf16
  u16* WB = XB + (size_t)8192 * 1024;         // [3072][1024] (Wq,Wk,Wv stacked)

  cast_all<<<11264, 256, 0, stream>>>(x, Wq, Wk, Wv, XB, WB);
  fused_qkv_attn<<<1024, 512, 0, stream>>>(XB, WB, mask, out);
}